// Round 9
// baseline (183.644 us; speedup 1.0000x reference)
//
#include <hip/hip_runtime.h>
#include <math.h>

#define N_V 12288
#define D_F 32
#define N_E 196608
#define KNN 6
#define EPSF 1e-12f

#define SEGS 24
#define JSEG (N_V / SEGS)          // 512 candidate columns per segment
#define SUBTILES (JSEG / 16)       // 32 j-subtiles per segment
#define ROWS_PER_BLOCK 128         // 4 waves x 32 query rows
#define ROW_BLOCKS (N_V / ROWS_PER_BLOCK)   // 96
#define TOPK_BLOCKS (ROW_BLOCKS * SEGS)     // 2304
#define EDGE_BLOCKS (N_E / 256)             // 768
#define MERGE_BLOCKS ((N_V * 4) / 256)      // 192

typedef __bf16 bf16x8 __attribute__((ext_vector_type(8)));
typedef float f32x4 __attribute__((ext_vector_type(4)));

static_assert(N_V % ROWS_PER_BLOCK == 0, "");
static_assert(SUBTILES % 2 == 0, "");
static_assert(JSEG % 32 == 0, "");

// descending sorted 6-list insert: 1 max + 5 med3
__device__ __forceinline__ void ins6(float s[KNN], float nv) {
    float y0 = fmaxf(s[0], nv);
    float y1 = __builtin_amdgcn_fmed3f(s[0], s[1], nv);
    float y2 = __builtin_amdgcn_fmed3f(s[1], s[2], nv);
    float y3 = __builtin_amdgcn_fmed3f(s[2], s[3], nv);
    float y4 = __builtin_amdgcn_fmed3f(s[3], s[4], nv);
    float y5 = __builtin_amdgcn_fmed3f(s[4], s[5], nv);
    s[0] = y0; s[1] = y1; s[2] = y2; s[3] = y3; s[4] = y4; s[5] = y5;
}

// truncate 8 fp32 -> bf16x8 (4x v_perm_b32: {hi16(f_odd), hi16(f_even)})
__device__ __forceinline__ bf16x8 pack_bf16x8(float4 f0, float4 f1) {
    uint4 r;
    r.x = __builtin_amdgcn_perm(__float_as_uint(f0.y), __float_as_uint(f0.x), 0x07060302u);
    r.y = __builtin_amdgcn_perm(__float_as_uint(f0.w), __float_as_uint(f0.z), 0x07060302u);
    r.z = __builtin_amdgcn_perm(__float_as_uint(f1.y), __float_as_uint(f1.x), 0x07060302u);
    r.w = __builtin_amdgcn_perm(__float_as_uint(f1.w), __float_as_uint(f1.z), 0x07060302u);
    return __builtin_bit_cast(bf16x8, r);
}

// ---------- kernel 1: edge-ey (blocks [0,EDGE)) + MFMA gram top-6 (rest) ----------
// A = candidate rows (j), B = query rows (i), both bf16-truncated on the fly.
// C[m=quad*4+reg][n=l16]; acc init = -0.5*sq_j from LDS => C = key directly.
__global__ __launch_bounds__(256, 8) void topk_mfma(
    const float* __restrict__ x, const int* __restrict__ ei,
    float* __restrict__ cand, unsigned* __restrict__ done,
    float* __restrict__ out) {
    const int t = threadIdx.x;

    if (blockIdx.x < EDGE_BLOCKS) {
        if (blockIdx.x == 0 && t == 0) *done = 0u;   // arm dispatch-2's gate
        // ---- edge-ey path: out[.,1] = 1 - exp(-||x_u - x_w||) ----
        const int e = blockIdx.x * 256 + t;
        const int u = ei[e];
        const int w = ei[N_E + e];
        const float4* xu = (const float4*)(x + (size_t)u * D_F);
        const float4* xw = (const float4*)(x + (size_t)w * D_F);
        float a0 = 0.f, a1 = 0.f, a2 = 0.f, a3 = 0.f;
#pragma unroll
        for (int d = 0; d < 8; ++d) {
            float4 p = xu[d], q = xw[d];
            float dx = p.x - q.x, dy = p.y - q.y, dz = p.z - q.z, dw = p.w - q.w;
            a0 += dx * dx; a1 += dy * dy; a2 += dz * dz; a3 += dw * dw;
        }
        const float enorm = sqrtf(fmaxf((a0 + a1) + (a2 + a3), EPSF));
        out[2 * (N_V + e) + 1] = 1.0f - expf(-enorm);
        return;
    }

    __shared__ float smsq[JSEG];   // -0.5*sq_j for this segment (2 KB)

    const int wave = t >> 6;
    const int lane = t & 63;
    const int quad = lane >> 4;
    const int l16 = lane & 15;

    const int bid = blockIdx.x - EDGE_BLOCKS;
    const int rb = bid % ROW_BLOCKS;
    const int seg = bid / ROW_BLOCKS;
    const int rowbase = rb * ROWS_PER_BLOCK + wave * 32;
    const int j0 = seg * JSEG;

    // ---- fill smsq: 8 threads/row, coalesced ----
    {
        const int part = t & 7;
        const int rsub = t >> 3;    // 0..31
#pragma unroll
        for (int pass = 0; pass < JSEG / 32; ++pass) {
            const int r = pass * 32 + rsub;
            float4 p = ((const float4*)(x + (size_t)(j0 + r) * D_F))[part];
            float s = p.x * p.x + p.y * p.y + p.z * p.z + p.w * p.w;
            s += __shfl_xor(s, 1, 64);
            s += __shfl_xor(s, 2, 64);
            s += __shfl_xor(s, 4, 64);
            if (part == 0) smsq[r] = -0.5f * s;
        }
    }
    __syncthreads();

    // ---- B fragments: query rows, truncated to bf16, register-resident ----
    bf16x8 bfrag[2];
#pragma unroll
    for (int rt = 0; rt < 2; ++rt) {
        const float4* xr = (const float4*)(x + (size_t)(rowbase + rt * 16 + l16) * D_F);
        bfrag[rt] = pack_bf16x8(xr[quad * 2], xr[quad * 2 + 1]);
    }

    float tk[2][KNN];
#pragma unroll
    for (int rt = 0; rt < 2; ++rt)
#pragma unroll
        for (int k = 0; k < KNN; ++k) tk[rt][k] = -3.0e38f;

    const float* aRow = x + (size_t)(j0 + l16) * D_F + quad * 8;

    for (int it = 0; it < SUBTILES; it += 2) {
#pragma unroll
        for (int u = 0; u < 2; ++u) {
            const float4 f0 = *(const float4*)(aRow + u * (16 * D_F));
            const float4 f1 = *(const float4*)(aRow + u * (16 * D_F) + 4);
            const bf16x8 a = pack_bf16x8(f0, f1);
            const float4 m = *(const float4*)&smsq[(it + u) * 16 + quad * 4];
            const f32x4 cinit = {m.x, m.y, m.z, m.w};
#pragma unroll
            for (int rt = 0; rt < 2; ++rt) {
                f32x4 c = __builtin_amdgcn_mfma_f32_16x16x32_bf16(a, bfrag[rt], cinit, 0, 0, 0);
#pragma unroll
                for (int reg = 0; reg < 4; ++reg)
                    ins6(tk[rt], c[reg]);
            }
        }
        aRow += 2 * 16 * D_F;
    }

    // ---- cross-quad merge via shuffles ----
#pragma unroll
    for (int rt = 0; rt < 2; ++rt) {
#pragma unroll
        for (int rnd = 0; rnd < 2; ++rnd) {
            const int mask = 16 << rnd;
            float b[KNN];
#pragma unroll
            for (int k = 0; k < KNN; ++k) b[k] = __shfl_xor(tk[rt][k], mask, 64);
#pragma unroll
            for (int k = 0; k < KNN; ++k) ins6(tk[rt], b[k]);
        }
    }

    if (quad == 0) {
#pragma unroll
        for (int rt = 0; rt < 2; ++rt) {
            const int g = rowbase + rt * 16 + l16;
            float* dst = cand + ((size_t)g * SEGS + seg) * KNN;
#pragma unroll
            for (int k = 0; k < KNN; ++k) dst[k] = tk[rt][k];
        }
    }
}

// ---------- kernel 2: merge_v (blocks [0,192)) + spin gate + edge_val (all) ----------
__global__ __launch_bounds__(256) void merge_edge(
    const float* __restrict__ x, const int* __restrict__ ei,
    const float* __restrict__ cand, float* __restrict__ v,
    unsigned* __restrict__ done, float* __restrict__ out) {
    const int t = threadIdx.x;
    const int b = blockIdx.x;

    if (b < MERGE_BLOCKS) {
        const int gid = b * 256 + t;   // 0..49151
        const int row = gid >> 2;
        const int h = gid & 3;
        // sq_i on the fly (4 threads/row, 8 dims each)
        const float4* xr = (const float4*)(x + (size_t)row * D_F);
        float4 p0 = xr[h * 2], p1 = xr[h * 2 + 1];
        float s = p0.x * p0.x + p0.y * p0.y + p0.z * p0.z + p0.w * p0.w
                + p1.x * p1.x + p1.y * p1.y + p1.z * p1.z + p1.w * p1.w;
        s += __shfl_xor(s, 1, 64);
        s += __shfl_xor(s, 2, 64);
        const float msqi = -0.5f * s;
        // merge this row's 24 segment lists (9 float4 per lane)
        const float4* c = (const float4*)(cand + (size_t)row * (SEGS * KNN));
        float mk[KNN];
#pragma unroll
        for (int k = 0; k < KNN; ++k) mk[k] = -3.0e38f;
#pragma unroll
        for (int s4 = 0; s4 < (SEGS * KNN / 4) / 4; ++s4) {
            float4 q = c[s4 * 4 + h];
            ins6(mk, q.x); ins6(mk, q.y); ins6(mk, q.z); ins6(mk, q.w);
        }
#pragma unroll
        for (int rnd = 0; rnd < 2; ++rnd) {
            const int mask = 1 << rnd;
            float bb[KNN];
#pragma unroll
            for (int k = 0; k < KNN; ++k) bb[k] = __shfl_xor(mk[k], mask, 64);
#pragma unroll
            for (int k = 0; k < KNN; ++k) ins6(mk, bb[k]);
        }
        if (h == 0) {
            float ssum = 0.f;
#pragma unroll
            for (int m = 1; m < KNN; ++m) {
                const float d2 = -2.0f * (mk[m] + msqi);   // sq_i - 2*key
                ssum += expf(-sqrtf(fmaxf(d2, EPSF)));
            }
            const float vi = 1.0f - ssum / (float)KNN;
            v[row] = vi;
            out[2 * row] = vi;
            out[2 * row + 1] = 0.0f;
        }
        __syncthreads();
        if (t == 0) {
            __threadfence();   // push v to the coherent point (192 fences total)
            __hip_atomic_fetch_add(done, 1u, __ATOMIC_RELEASE, __HIP_MEMORY_SCOPE_AGENT);
        }
    }

    // ---- gate: wait for all 192 merge blocks, then edge values ----
    if (t == 0) {
        while (__hip_atomic_load(done, __ATOMIC_RELAXED, __HIP_MEMORY_SCOPE_AGENT) < MERGE_BLOCKS)
            __builtin_amdgcn_s_sleep(1);
        __threadfence();   // acquire: invalidate stale v lines
    }
    __syncthreads();

    const int e = b * 256 + t;
    const int u = ei[e];
    const int w = ei[N_E + e];
    out[2 * (N_V + e) + 0] = fmaxf(v[u], v[w]);
}

extern "C" void kernel_launch(void* const* d_in, const int* in_sizes, int n_in,
                              void* d_out, int out_size, void* d_ws, size_t ws_size,
                              hipStream_t stream) {
    const float* x = (const float*)d_in[0];
    const int* ei = (const int*)d_in[1];
    float* out = (float*)d_out;
    char* ws = (char*)d_ws;

    float* v = (float*)ws;                          // 49152 B
    float* cand = (float*)(ws + 49152);             // 7077888 B
    unsigned* done = (unsigned*)(ws + 49152 + 7077888);  // 4 B  (~7.1 MB total)

    topk_mfma<<<EDGE_BLOCKS + TOPK_BLOCKS, 256, 0, stream>>>(x, ei, cand, done, out);

    merge_edge<<<EDGE_BLOCKS, 256, 0, stream>>>(x, ei, cand, v, done, out);
}

// Round 10
// 118.313 us; speedup vs baseline: 1.5522x; 1.5522x over previous
//
#include <hip/hip_runtime.h>
#include <math.h>

#define N_V 12288
#define D_F 32
#define N_E 196608
#define KNN 6
#define EPSF 1e-12f

#define SEGS 24
#define JSEG (N_V / SEGS)          // 512 candidate columns per segment
#define SUBTILES (JSEG / 16)       // 32 j-subtiles per segment
#define RT 4                       // 16-row query tiles per wave (64 rows/wave)
#define ROWS_PER_BLOCK 256         // 4 waves x 64 query rows
#define ROW_BLOCKS (N_V / ROWS_PER_BLOCK)   // 48
#define TOPK_BLOCKS (ROW_BLOCKS * SEGS)     // 1152
#define EDGE_BLOCKS (N_E / 256)             // 768

typedef __bf16 bf16x8 __attribute__((ext_vector_type(8)));
typedef float f32x4 __attribute__((ext_vector_type(4)));

static_assert(N_V % ROWS_PER_BLOCK == 0, "");
static_assert(SUBTILES % 2 == 0, "");

__device__ __forceinline__ unsigned short f2bf(float f) {
    unsigned u = __builtin_bit_cast(unsigned, f);
    unsigned r = u + 0x7fffu + ((u >> 16) & 1u);   // RNE
    return (unsigned short)(r >> 16);
}

// descending sorted 6-list insert: 1 max + 5 med3
__device__ __forceinline__ void ins6(float s[KNN], float nv) {
    float y0 = fmaxf(s[0], nv);
    float y1 = __builtin_amdgcn_fmed3f(s[0], s[1], nv);
    float y2 = __builtin_amdgcn_fmed3f(s[1], s[2], nv);
    float y3 = __builtin_amdgcn_fmed3f(s[2], s[3], nv);
    float y4 = __builtin_amdgcn_fmed3f(s[3], s[4], nv);
    float y5 = __builtin_amdgcn_fmed3f(s[4], s[5], nv);
    s[0] = y0; s[1] = y1; s[2] = y2; s[3] = y3; s[4] = y4; s[5] = y5;
}

// ---------- kernel 0: bf16 convert + msq(-0.5*sq), 8 threads/row ----------
__global__ __launch_bounds__(256) void prep_kernel(const float* __restrict__ x,
                                                   unsigned short* __restrict__ xb,
                                                   float* __restrict__ msq) {
    const int gid = blockIdx.x * 256 + threadIdx.x;   // 0..98303
    const int row = gid >> 3;
    const int h = gid & 7;
    float4 p = ((const float4*)(x + (size_t)row * D_F))[h];
    float s = p.x * p.x + p.y * p.y + p.z * p.z + p.w * p.w;
    s += __shfl_xor(s, 1, 64);
    s += __shfl_xor(s, 2, 64);
    s += __shfl_xor(s, 4, 64);
    const unsigned lo = (unsigned)f2bf(p.x) | ((unsigned)f2bf(p.y) << 16);
    const unsigned hi = (unsigned)f2bf(p.z) | ((unsigned)f2bf(p.w) << 16);
    ((uint2*)xb)[gid] = make_uint2(lo, hi);
    if (h == 0) msq[row] = -0.5f * s;
}

// ---------- kernel 1: edge-ey (blocks [0,EDGE)) + MFMA gram top-6 (rest) ----------
// A = candidate rows (j), B = query rows (i). C[m=quad*4+reg][n=l16]:
// lane's query row = rowbase + rt*16 + l16, candidates j = col0 + quad*4 + reg.
// acc init = msq[j] => C = dot - 0.5*sq_j (selection key; larger == closer).
// RT=4 query tiles per wave: each A/msq load feeds 4 MFMAs + 96 ins6 ops,
// halving hot-loop load frequency vs RT=2 (latency-bound fix, R10).
__global__ __launch_bounds__(256, 6) void topk_mfma(
    const unsigned short* __restrict__ xb, const float* __restrict__ msq,
    float* __restrict__ cand, const float* __restrict__ x,
    const int* __restrict__ ei, float* __restrict__ out) {
    const int t = threadIdx.x;

    if (blockIdx.x < EDGE_BLOCKS) {
        // ---- edge-ey path: out[.,1] = 1 - exp(-||x_u - x_w||) ----
        const int e = blockIdx.x * 256 + t;
        const int u = ei[e];
        const int w = ei[N_E + e];
        const float4* xu = (const float4*)(x + (size_t)u * D_F);
        const float4* xw = (const float4*)(x + (size_t)w * D_F);
        float a0 = 0.f, a1 = 0.f, a2 = 0.f, a3 = 0.f;
#pragma unroll
        for (int d = 0; d < 8; ++d) {
            float4 p = xu[d], q = xw[d];
            float dx = p.x - q.x, dy = p.y - q.y, dz = p.z - q.z, dw = p.w - q.w;
            a0 += dx * dx; a1 += dy * dy; a2 += dz * dz; a3 += dw * dw;
        }
        const float enorm = sqrtf(fmaxf((a0 + a1) + (a2 + a3), EPSF));
        out[2 * (N_V + e) + 1] = 1.0f - expf(-enorm);
        return;
    }

    const int wave = t >> 6;
    const int lane = t & 63;
    const int quad = lane >> 4;
    const int l16 = lane & 15;

    const int bid = blockIdx.x - EDGE_BLOCKS;
    const int rb = bid % ROW_BLOCKS;
    const int seg = bid / ROW_BLOCKS;
    const int rowbase = rb * ROWS_PER_BLOCK + wave * (RT * 16);
    const int j0 = seg * JSEG;

    // B fragments: query rows, register-resident
    bf16x8 bfrag[RT];
#pragma unroll
    for (int rt = 0; rt < RT; ++rt)
        bfrag[rt] = *reinterpret_cast<const bf16x8*>(
            xb + (size_t)(rowbase + rt * 16 + l16) * D_F + quad * 8);

    float tk[RT][KNN];
#pragma unroll
    for (int rt = 0; rt < RT; ++rt)
#pragma unroll
        for (int k = 0; k < KNN; ++k) tk[rt][k] = -3.0e38f;

    const unsigned short* aptr = xb + (size_t)(j0 + l16) * D_F + quad * 8;
    const float* mptr = msq + j0 + quad * 4;

    for (int it = 0; it < SUBTILES; it += 2) {
#pragma unroll
        for (int u = 0; u < 2; ++u) {
            const bf16x8 a = *reinterpret_cast<const bf16x8*>(aptr + u * (16 * D_F));
            const float4 m = *reinterpret_cast<const float4*>(mptr + u * 16);
            const f32x4 cinit = {m.x, m.y, m.z, m.w};
#pragma unroll
            for (int rt = 0; rt < RT; ++rt) {
                f32x4 c = __builtin_amdgcn_mfma_f32_16x16x32_bf16(a, bfrag[rt], cinit, 0, 0, 0);
#pragma unroll
                for (int reg = 0; reg < 4; ++reg)
                    ins6(tk[rt], c[reg]);
            }
        }
        aptr += 2 * 16 * D_F;
        mptr += 2 * 16;
    }

    // ---- cross-quad merge via shuffles (row's lists live in 4 quads, same l16) ----
#pragma unroll
    for (int rt = 0; rt < RT; ++rt) {
#pragma unroll
        for (int rnd = 0; rnd < 2; ++rnd) {
            const int mask = 16 << rnd;
            float b[KNN];
#pragma unroll
            for (int k = 0; k < KNN; ++k) b[k] = __shfl_xor(tk[rt][k], mask, 64);
#pragma unroll
            for (int k = 0; k < KNN; ++k) ins6(tk[rt], b[k]);
        }
    }

    if (quad == 0) {
#pragma unroll
        for (int rt = 0; rt < RT; ++rt) {
            const int g = rowbase + rt * 16 + l16;
            float* dst = cand + ((size_t)g * SEGS + seg) * KNN;
#pragma unroll
            for (int k = 0; k < KNN; ++k) dst[k] = tk[rt][k];
        }
    }
}

// ---------- kernel 2: merge per-segment keys -> v, 4 threads/row ----------
__global__ __launch_bounds__(256) void merge_v(const float* __restrict__ cand,
                                               const float* __restrict__ msq,
                                               float* __restrict__ v,
                                               float* __restrict__ out) {
    const int gid = blockIdx.x * 256 + threadIdx.x;   // 0..49151
    const int row = gid >> 2;
    const int h = gid & 3;
    const float4* c = (const float4*)(cand + (size_t)row * (SEGS * KNN));  // 36 x float4
    float mk[KNN];
#pragma unroll
    for (int k = 0; k < KNN; ++k) mk[k] = -3.0e38f;
#pragma unroll
    for (int s4 = 0; s4 < (SEGS * KNN / 4) / 4; ++s4) {   // 9 each
        float4 q = c[s4 * 4 + h];
        ins6(mk, q.x); ins6(mk, q.y); ins6(mk, q.z); ins6(mk, q.w);
    }
    // merge across the 4 lanes of this row (consecutive lanes, same wave)
#pragma unroll
    for (int rnd = 0; rnd < 2; ++rnd) {
        const int mask = 1 << rnd;
        float b[KNN];
#pragma unroll
        for (int k = 0; k < KNN; ++k) b[k] = __shfl_xor(mk[k], mask, 64);
#pragma unroll
        for (int k = 0; k < KNN; ++k) ins6(mk, b[k]);
    }
    if (h == 0) {
        const float msqi = msq[row];
        float ssum = 0.f;
#pragma unroll
        for (int m = 1; m < KNN; ++m) {
            const float d2 = -2.0f * (mk[m] + msqi);   // sq_i - 2*key
            ssum += expf(-sqrtf(fmaxf(d2, EPSF)));
        }
        const float vi = 1.0f - ssum / (float)KNN;
        v[row] = vi;
        out[2 * row] = vi;
        out[2 * row + 1] = 0.0f;
    }
}

// ---------- kernel 3: edge value = max(v[u], v[w]) ----------
__global__ __launch_bounds__(256) void edge_val(const int* __restrict__ ei,
                                                const float* __restrict__ v,
                                                float* __restrict__ out) {
    const int e = blockIdx.x * 256 + threadIdx.x;
    const int u = ei[e];
    const int w = ei[N_E + e];
    out[2 * (N_V + e) + 0] = fmaxf(v[u], v[w]);
}

extern "C" void kernel_launch(void* const* d_in, const int* in_sizes, int n_in,
                              void* d_out, int out_size, void* d_ws, size_t ws_size,
                              hipStream_t stream) {
    const float* x = (const float*)d_in[0];
    const int* ei = (const int*)d_in[1];
    float* out = (float*)d_out;
    char* ws = (char*)d_ws;

    unsigned short* xb = (unsigned short*)ws;                  // 786432 B
    float* msq = (float*)(ws + 786432);                        // 49152 B
    float* v   = (float*)(ws + 786432 + 49152);                // 49152 B
    float* cand = (float*)(ws + 786432 + 2 * 49152);           // 7077888 B (~7.97 MB total)

    prep_kernel<<<(N_V * 8) / 256, 256, 0, stream>>>(x, xb, msq);

    topk_mfma<<<EDGE_BLOCKS + TOPK_BLOCKS, 256, 0, stream>>>(xb, msq, cand, x, ei, out);

    merge_v<<<(N_V * 4) / 256, 256, 0, stream>>>(cand, msq, v, out);

    edge_val<<<N_E / 256, 256, 0, stream>>>(ei, v, out);
}